// Round 2
// baseline (432.987 us; speedup 1.0000x reference)
//
#include <hip/hip_runtime.h>
#include <hip/hip_bf16.h>

#define D 1024
#define H 16
#define DH 64
#define KN 32768
#define EPS 1e-5f

__device__ __forceinline__ float wave_sum(float v){
  #pragma unroll
  for (int off = 32; off; off >>= 1) v += __shfl_xor(v, off, 64);
  return v;
}

// device-scope grid barrier: all blocks co-resident (grid 256 x 256thr << capacity)
__device__ __forceinline__ void gbar(unsigned int* bar, unsigned int target){
  __syncthreads();
  if (threadIdx.x == 0){
    __threadfence();                       // release prior global stores
    atomicAdd(bar, 1u);                    // device scope by default
    while (__hip_atomic_load(bar, __ATOMIC_RELAXED, __HIP_MEMORY_SCOPE_AGENT) < target){
      __builtin_amdgcn_s_sleep(2);
    }
  }
  __syncthreads();
  __threadfence();                         // acquire: refetch others' data
}

#define GLL(gp, lp) __builtin_amdgcn_global_load_lds((const __attribute__((address_space(1))) void*)(gp), (__attribute__((address_space(3))) void*)(lp), 16, 0, 0)

// K1: merged qproj+qk. 64 blocks (head h = b>>2, col slice sl = b&3).
// Phase 1: qh[0..63] = query . wq_rows (redundant per sl-block; +12MB L2 reads, -1 launch).
// Phase 2: qk[h][col] = sum_j qh[j]*wk[h*64+j][col]; sb[h] = qh . bk_h.
__global__ __launch_bounds__(256) void g_qk(const float* __restrict__ query,
                                            const float* __restrict__ ipw, const float* __restrict__ ipb,
                                            float* __restrict__ qk, float* __restrict__ sb,
                                            unsigned int* __restrict__ bar){
  int b = blockIdx.x, t = threadIdx.x;
  int h = b >> 2, sl = b & 3;
  int w = t >> 6, ci = t & 63;
  __shared__ float qh[DH];
  __shared__ float4 red[256];
  if (b == 0 && t == 0) *bar = 0u;        // reset grid barrier for g_tail (each iter)

  // phase 1: 16 q-rows per wave, 4 rows in flight (16 lanes per row)
  {
    int cq = ci & 15, rq = ci >> 4;
    const float4* qv = (const float4*)query;
    #pragma unroll
    for (int b4 = 0; b4 < 4; b4++){
      int jr = w*16 + b4*4 + rq;
      const float4* wr = (const float4*)(ipw + (size_t)(h*DH + jr)*D);
      float a = 0.f;
      #pragma unroll
      for (int c = 0; c < 4; c++){
        float4 ww = wr[c*16 + cq], qq = qv[c*16 + cq];
        a += ww.x*qq.x + ww.y*qq.y + ww.z*qq.z + ww.w*qq.w;
      }
      a += __shfl_xor(a, 1, 64);
      a += __shfl_xor(a, 2, 64);
      a += __shfl_xor(a, 4, 64);
      a += __shfl_xor(a, 8, 64);
      if (cq == 0) qh[jr] = a + ipb[h*DH + jr];
    }
  }
  __syncthreads();

  if (t < DH){
    float p = qh[t] * ipb[D + h*DH + t];
    p = wave_sum(p);
    if (t == 0 && sl == 0) sb[h] = p;
  }
  float4 acc = make_float4(0.f,0.f,0.f,0.f);
  for (int jj = 0; jj < 16; jj++){
    int j = w*16 + jj;
    float4 ww = *((const float4*)(ipw + (size_t)(D + h*DH + j)*D) + sl*64 + ci);
    float qj = qh[j];
    acc.x += qj*ww.x; acc.y += qj*ww.y; acc.z += qj*ww.z; acc.w += qj*ww.w;
  }
  red[t] = acc;
  __syncthreads();
  if (w == 0){
    float4 a = red[ci], b1 = red[64+ci], c1 = red[128+ci], d1 = red[192+ci];
    float4 r = make_float4(a.x+b1.x+c1.x+d1.x, a.y+b1.y+c1.y+d1.y,
                           a.z+b1.z+c1.z+d1.z, a.w+b1.w+c1.w+d1.w);
    ((float4*)(qk + h*D))[sl*64 + ci] = r;
  }
}

// scatter-reduce butterfly: 4 per-head partials -> head g=(ci>>4) total in all lanes of group g
__device__ __forceinline__ float bf4(float s0, float s1, float s2, float s3, int ci){
  const bool lo32 = (ci & 32) == 0;
  float za = lo32 ? s2 : s0;
  float ka = lo32 ? s0 : s2;
  float u02 = ka + __shfl_xor(za, 32, 64);
  float zb = lo32 ? s3 : s1;
  float kb = lo32 ? s1 : s3;
  float u13 = kb + __shfl_xor(zb, 32, 64);
  const bool lo16 = (ci & 16) == 0;
  float zc = lo16 ? u13 : u02;
  float kc = lo16 ? u02 : u13;
  float v = kc + __shfl_xor(zc, 16, 64);
  v += __shfl_xor(v, 8, 64);
  v += __shfl_xor(v, 4, 64);
  v += __shfl_xor(v, 2, 64);
  v += __shfl_xor(v, 1, 64);
  return v;
}

// K2: fused scoreless attention v3. 4 waves, wave w owns heads {4w..4w+3}.
// Row-PAIR software pipeline: two independent butterfly chains interleave to
// hide cross-lane latency (was unroll 1 -> serial chains, VALUBusy 41%).
__global__ __launch_bounds__(256, 2) void g_attn(const float* __restrict__ nbr, const float* __restrict__ qk,
                       const float* __restrict__ sb, float* __restrict__ lpart,
                       float* __restrict__ part, int rows_per_blk){
  __shared__ __align__(16) float tile[2][8*D];   // 64 KiB -> 2 blocks/CU
  const int t = threadIdx.x;
  const int w = t >> 6, ci = t & 63;
  const int wb = t & ~63;
  const int g = (ci >> 4) & 3;
  const float sbl = sb[w*4 + g];

  float qk0[16], qk1[16], qk2[16], qk3[16];
  {
    const float4* p0 = (const float4*)(qk + (w*4+0)*D);
    const float4* p1 = (const float4*)(qk + (w*4+1)*D);
    const float4* p2 = (const float4*)(qk + (w*4+2)*D);
    const float4* p3 = (const float4*)(qk + (w*4+3)*D);
    #pragma unroll
    for (int c = 0; c < 4; c++){
      float4 f;
      f = p0[c*64 + ci]; qk0[4*c]=f.x; qk0[4*c+1]=f.y; qk0[4*c+2]=f.z; qk0[4*c+3]=f.w;
      f = p1[c*64 + ci]; qk1[4*c]=f.x; qk1[4*c+1]=f.y; qk1[4*c+2]=f.z; qk1[4*c+3]=f.w;
      f = p2[c*64 + ci]; qk2[4*c]=f.x; qk2[4*c+1]=f.y; qk2[4*c+2]=f.z; qk2[4*c+3]=f.w;
      f = p3[c*64 + ci]; qk3[4*c]=f.x; qk3[4*c+1]=f.y; qk3[4*c+2]=f.z; qk3[4*c+3]=f.w;
    }
  }
  float acc0[16], acc1[16], acc2[16], acc3[16];
  #pragma unroll
  for (int i = 0; i < 16; i++){ acc0[i]=0.f; acc1[i]=0.f; acc2[i]=0.f; acc3[i]=0.f; }
  float lsum = 0.f;

  const int k0 = blockIdx.x * rows_per_blk;
  const int ntiles = rows_per_blk >> 3;
  const uint4* gb = (const uint4*)nbr;

  {
    const uint4* gsrc = gb + (size_t)k0*256;
    #pragma unroll
    for (int i = 0; i < 8; i++) GLL(gsrc + i*256 + t, &tile[0][(i*256 + wb)*4]);
  }
  __syncthreads();

  #pragma unroll 1
  for (int tl = 0; tl < ntiles; tl++){
    int cur = tl & 1;
    if (tl + 1 < ntiles){
      const uint4* gsrc = gb + (size_t)(k0 + (tl+1)*8)*256;
      #pragma unroll
      for (int i = 0; i < 8; i++) GLL(gsrc + i*256 + t, &tile[cur^1][(i*256 + wb)*4]);
    }
    __builtin_amdgcn_s_setprio(1);
    #pragma unroll 1
    for (int r = 0; r < 8; r += 2){
      const float4* rowA = (const float4*)(tile[cur]) + r*256;
      float xfA[16], xfB[16];
      float sA0=0.f,sA1=0.f,sA2=0.f,sA3=0.f;
      float sB0=0.f,sB1=0.f,sB2=0.f,sB3=0.f;
      #pragma unroll
      for (int c = 0; c < 4; c++){
        float4 a = rowA[c*64 + ci];
        xfA[4*c]=a.x; xfA[4*c+1]=a.y; xfA[4*c+2]=a.z; xfA[4*c+3]=a.w;
        sA0 += a.x*qk0[4*c] + a.y*qk0[4*c+1] + a.z*qk0[4*c+2] + a.w*qk0[4*c+3];
        sA1 += a.x*qk1[4*c] + a.y*qk1[4*c+1] + a.z*qk1[4*c+2] + a.w*qk1[4*c+3];
        sA2 += a.x*qk2[4*c] + a.y*qk2[4*c+1] + a.z*qk2[4*c+2] + a.w*qk2[4*c+3];
        sA3 += a.x*qk3[4*c] + a.y*qk3[4*c+1] + a.z*qk3[4*c+2] + a.w*qk3[4*c+3];
      }
      #pragma unroll
      for (int c = 0; c < 4; c++){
        float4 a = rowA[256 + c*64 + ci];
        xfB[4*c]=a.x; xfB[4*c+1]=a.y; xfB[4*c+2]=a.z; xfB[4*c+3]=a.w;
        sB0 += a.x*qk0[4*c] + a.y*qk0[4*c+1] + a.z*qk0[4*c+2] + a.w*qk0[4*c+3];
        sB1 += a.x*qk1[4*c] + a.y*qk1[4*c+1] + a.z*qk1[4*c+2] + a.w*qk1[4*c+3];
        sB2 += a.x*qk2[4*c] + a.y*qk2[4*c+1] + a.z*qk2[4*c+2] + a.w*qk2[4*c+3];
        sB3 += a.x*qk3[4*c] + a.y*qk3[4*c+1] + a.z*qk3[4*c+2] + a.w*qk3[4*c+3];
      }
      float vA = bf4(sA0, sA1, sA2, sA3, ci);
      float vB = bf4(sB0, sB1, sB2, sB3, ci);
      float pA = __expf((vA + sbl)*0.125f);
      float pB = __expf((vB + sbl)*0.125f);
      lsum += pA + pB;
      float pA0 = __shfl(pA, 0, 64), pA1 = __shfl(pA, 16, 64);
      float pA2 = __shfl(pA, 32, 64), pA3 = __shfl(pA, 48, 64);
      float pB0 = __shfl(pB, 0, 64), pB1 = __shfl(pB, 16, 64);
      float pB2 = __shfl(pB, 32, 64), pB3 = __shfl(pB, 48, 64);
      #pragma unroll
      for (int j = 0; j < 16; j++){
        acc0[j] += pA0*xfA[j] + pB0*xfB[j];
        acc1[j] += pA1*xfA[j] + pB1*xfB[j];
        acc2[j] += pA2*xfA[j] + pB2*xfB[j];
        acc3[j] += pA3*xfA[j] + pB3*xfB[j];
      }
    }
    __builtin_amdgcn_s_setprio(0);
    __syncthreads();
  }

  if ((ci & 15) == 0) lpart[blockIdx.x*H + w*4 + g] = lsum;
  float4* o = (float4*)(part + (size_t)blockIdx.x*(H*D) + (size_t)(w*4)*D);
  #pragma unroll
  for (int c = 0; c < 4; c++){
    o[0*256 + c*64 + ci] = make_float4(acc0[4*c], acc0[4*c+1], acc0[4*c+2], acc0[4*c+3]);
    o[1*256 + c*64 + ci] = make_float4(acc1[4*c], acc1[4*c+1], acc1[4*c+2], acc1[4*c+3]);
    o[2*256 + c*64 + ci] = make_float4(acc2[4*c], acc2[4*c+1], acc2[4*c+2], acc2[4*c+3]);
    o[3*256 + c*64 + ci] = make_float4(acc3[4*c], acc3[4*c+1], acc3[4*c+2], acc3[4*c+3]);
  }
}

// K3: fused tail. 256 blocks x 256 thr, all co-resident; manual grid barrier between phases.
// P0 red -> P1 ctx -> P2 attnout(xb) -> P3 LN1+FFN1 -> P4 FFN2 -> P5 LN2 (block 0).
__global__ __launch_bounds__(256) void g_tail(
    const float* __restrict__ part, const float* __restrict__ lpart,
    const float* __restrict__ ipw, const float* __restrict__ ipb,
    const float* __restrict__ opw, const float* __restrict__ opb,
    const float* __restrict__ query,
    const float* __restrict__ w1, const float* __restrict__ b1,
    const float* __restrict__ w2, const float* __restrict__ b2v,
    const float* __restrict__ g1, const float* __restrict__ be1,
    const float* __restrict__ g2, const float* __restrict__ be2,
    float* __restrict__ nb, float* __restrict__ lh,
    float* __restrict__ ctx, float* __restrict__ xb,
    float* __restrict__ h1, float* __restrict__ y,
    float* __restrict__ out, unsigned int* __restrict__ bar, int nblk){
  const int b = blockIdx.x, t = threadIdx.x;
  const int w = t >> 6, l = t & 63;
  __shared__ __align__(16) float xs[D];
  __shared__ float red[256];

  // P0: nb[o] = sum over part blocks (4-way K-split); block 0 also reduces lpart -> lh
  {
    int o0 = b*64;
    int per = nblk >> 2;
    float s = 0.f;
    #pragma unroll 8
    for (int k = 0; k < per; k++) s += part[(size_t)(w*per + k)*(H*D) + o0 + l];
    red[t] = s;
    __syncthreads();
    if (t < 64) nb[o0 + t] = red[t] + red[64+t] + red[128+t] + red[192+t];
    if (b == 0){
      __syncthreads();
      int hh = t & 15, cs2 = t >> 4, per2 = nblk >> 4;
      float s2 = 0.f;
      for (int k = 0; k < per2; k++) s2 += lpart[(cs2*per2 + k)*H + hh];
      red[t] = s2;
      __syncthreads();
      if (t < 16){
        float a = 0.f;
        #pragma unroll
        for (int i = 0; i < 16; i++) a += red[i*16 + t];
        lh[t] = a;
      }
    }
  }
  gbar(bar, 256);

  // P1: ctx[j] = wv_row(j) . nb_h / lh[h] + bv[j]   (4 dots per block, wave each)
  {
    int j = b*4 + w, hh = j >> 6;
    const float4* wv = (const float4*)(ipw + (size_t)(2*D + j)*D + l*16);
    const float4* nv = (const float4*)(nb + hh*D + l*16);
    float acc = 0.f;
    #pragma unroll
    for (int c = 0; c < 4; c++){
      float4 bb = wv[c], nn = nv[c];
      acc += bb.x*nn.x + bb.y*nn.y + bb.z*nn.z + bb.w*nn.w;
    }
    acc = wave_sum(acc);
    if (l == 0) ctx[j] = acc/lh[hh] + ipb[2*D + j];
  }
  gbar(bar, 512);

  // P2: xb[j] = query[j] + opw_row(j) . ctx + opb[j]
  {
    int j = b*4 + w;
    const float4* wv = (const float4*)(opw + (size_t)j*D + l*16);
    const float4* cv = (const float4*)(ctx + l*16);
    float acc = 0.f;
    #pragma unroll
    for (int c = 0; c < 4; c++){
      float4 bb = wv[c], cc = cv[c];
      acc += bb.x*cc.x + bb.y*cc.y + bb.z*cc.z + bb.w*cc.w;
    }
    acc = wave_sum(acc);
    if (l == 0) xb[j] = query[j] + acc + opb[j];
  }
  gbar(bar, 768);

  // P3: LN1 (per-block, into xs) + 16 rows of FFN1 (gelu) -> h1
  {
    float4 v = ((const float4*)xb)[t];
    float s = wave_sum(v.x + v.y + v.z + v.w);
    if (l == 0) red[w] = s;
    __syncthreads();
    float m = (red[0]+red[1]+red[2]+red[3]) * (1.0f/D);
    float4 dd = make_float4(v.x-m, v.y-m, v.z-m, v.w-m);
    float s2 = wave_sum(dd.x*dd.x + dd.y*dd.y + dd.z*dd.z + dd.w*dd.w);
    if (l == 0) red[4 + w] = s2;
    __syncthreads();
    float var = (red[4]+red[5]+red[6]+red[7]) * (1.0f/D);
    float rs = rsqrtf(var + EPS);
    float4 gg = ((const float4*)g1)[t], bb = ((const float4*)be1)[t];
    float4 r = make_float4(dd.x*rs*gg.x + bb.x, dd.y*rs*gg.y + bb.y,
                           dd.z*rs*gg.z + bb.z, dd.w*rs*gg.w + bb.w);
    ((float4*)xs)[t] = r;
    __syncthreads();
    const float4* xs4 = (const float4*)xs;
    #pragma unroll 1
    for (int rr = 0; rr < 4; rr++){
      int j = b*16 + w*4 + rr;
      const float4* wr = (const float4*)(w1 + (size_t)j*D);
      float a = 0.f;
      #pragma unroll
      for (int c = 0; c < 4; c++){
        float4 ww = wr[c*64 + l], xx = xs4[c*64 + l];
        a += ww.x*xx.x + ww.y*xx.y + ww.z*xx.z + ww.w*xx.w;
      }
      a = wave_sum(a);
      if (l == 0){
        float z = a + b1[j];
        h1[j] = 0.5f*z*(1.0f + erff(z*0.70710678118654752f));
      }
    }
  }
  gbar(bar, 1024);

  // P4: y[j] = w2_row(j) . h1 + b2[j]
  {
    int j = b*4 + w;
    const float4* wv = (const float4*)(w2 + (size_t)j*4096 + l*64);
    const float4* hv = (const float4*)(h1 + l*64);
    float acc = 0.f;
    #pragma unroll
    for (int c = 0; c < 16; c++){
      float4 bb = wv[c], hh2 = hv[c];
      acc += bb.x*hh2.x + bb.y*hh2.y + bb.z*hh2.z + bb.w*hh2.w;
    }
    acc = wave_sum(acc);
    if (l == 0) y[j] = acc + b2v[j];
  }
  gbar(bar, 1280);

  // P5: block 0 only: out = LN(xs + y)*g2 + be2   (xs = LN1 result kept in LDS)
  if (b == 0){
    float4 xv = ((const float4*)xs)[t];
    float4 yv = ((const float4*)y)[t];
    float4 v = make_float4(xv.x+yv.x, xv.y+yv.y, xv.z+yv.z, xv.w+yv.w);
    float s = wave_sum(v.x + v.y + v.z + v.w);
    if (l == 0) red[w] = s;
    __syncthreads();
    float m = (red[0]+red[1]+red[2]+red[3]) * (1.0f/D);
    float4 dd = make_float4(v.x-m, v.y-m, v.z-m, v.w-m);
    float s2 = wave_sum(dd.x*dd.x + dd.y*dd.y + dd.z*dd.z + dd.w*dd.w);
    if (l == 0) red[4 + w] = s2;
    __syncthreads();
    float var = (red[4]+red[5]+red[6]+red[7]) * (1.0f/D);
    float rs = rsqrtf(var + EPS);
    float4 gg = ((const float4*)g2)[t], bb = ((const float4*)be2)[t];
    ((float4*)out)[t] = make_float4(dd.x*rs*gg.x + bb.x, dd.y*rs*gg.y + bb.y,
                                    dd.z*rs*gg.z + bb.z, dd.w*rs*gg.w + bb.w);
  }
}

extern "C" void kernel_launch(void* const* d_in, const int* in_sizes, int n_in,
                              void* d_out, int out_size, void* d_ws, size_t ws_size,
                              hipStream_t stream) {
  const float* query = (const float*)d_in[0];
  const float* nbr   = (const float*)d_in[1];
  const float* ipw   = (const float*)d_in[2];
  const float* ipb   = (const float*)d_in[3];
  const float* opw   = (const float*)d_in[4];
  const float* opb   = (const float*)d_in[5];
  const float* w1    = (const float*)d_in[6];
  const float* b1    = (const float*)d_in[7];
  const float* w2    = (const float*)d_in[8];
  const float* b2v   = (const float*)d_in[9];
  const float* g1    = (const float*)d_in[10];
  const float* be1   = (const float*)d_in[11];
  const float* g2    = (const float*)d_in[12];
  const float* be2   = (const float*)d_in[13];

  float* ws    = (float*)d_ws;
  float* qk    = ws;               // 16384
  float* sb    = qk + H*D;         // 16
  float* lh    = sb + 16;          // 16
  float* ctx   = lh + 16;          // 1024
  float* xb    = ctx + D;          // 1024
  float* h1    = xb + D;           // 4096
  float* y     = h1 + 4*D;         // 1024
  float* nb    = y + D;            // 16384
  unsigned int* bar = (unsigned int*)(nb + H*D);  // 16 slots (padded)
  float* lpart = nb + H*D + 16;    // 512*16 = 8192 (max)
  float* part  = lpart + 8192;     // nblk*16384

  size_t fixed_bytes = (size_t)(part - ws) * 4;
  int nblk = 512;
  while (nblk > 64 && fixed_bytes + (size_t)nblk*H*D*4 > ws_size) nblk >>= 1;
  int rows_per_blk = KN / nblk;

  g_qk  <<<64, 256, 0, stream>>>(query, ipw, ipb, qk, sb, bar);
  g_attn<<<nblk, 256, 0, stream>>>(nbr, qk, sb, lpart, part, rows_per_blk);
  g_tail<<<256, 256, 0, stream>>>(part, lpart, ipw, ipb, opw, opb, query,
                                  w1, b1, w2, b2v, g1, be1, g2, be2,
                                  nb, lh, ctx, xb, h1, y, (float*)d_out, bar, nblk);
}

// Round 3
// 306.858 us; speedup vs baseline: 1.4110x; 1.4110x over previous
//
#include <hip/hip_runtime.h>
#include <hip/hip_bf16.h>

#define D 1024
#define H 16
#define DH 64
#define KN 32768
#define EPS 1e-5f

__device__ __forceinline__ float wave_sum(float v){
  #pragma unroll
  for (int off = 32; off; off >>= 1) v += __shfl_xor(v, off, 64);
  return v;
}

#define GLL(gp, lp) __builtin_amdgcn_global_load_lds((const __attribute__((address_space(1))) void*)(gp), (__attribute__((address_space(3))) void*)(lp), 16, 0, 0)

// K1: merged qproj+qk. 64 blocks (head h = b>>2, col slice sl = b&3).
// Phase 1: wave w computes q rows w*16..w*16+15 with EXACT round-1 per-row order
// (lane ci owns elements ci*16..ci*16+15, sequential float4s, full wave_sum).
// Phase 2: qk[h][col] = sum_j qh[j]*wk[h*64+j][col]; sb[h] = qh . bk_h.
__global__ __launch_bounds__(256) void g_qk(const float* __restrict__ query,
                                            const float* __restrict__ ipw, const float* __restrict__ ipb,
                                            float* __restrict__ qk, float* __restrict__ sb){
  int b = blockIdx.x, t = threadIdx.x;
  int h = b >> 2, sl = b & 3;
  int w = t >> 6, ci = t & 63;
  __shared__ float qh[DH];
  __shared__ float4 red[256];

  // phase 1: 16 rows per wave, 2-row ILP (per-row math identical to round-1 g_qproj)
  {
    const float4* qv = (const float4*)(query + ci*16);
    #pragma unroll 1
    for (int jj = 0; jj < 16; jj += 2){
      int j0 = h*DH + w*16 + jj;
      const float4* w0 = (const float4*)(ipw + (size_t)j0*D + ci*16);
      const float4* w1r = (const float4*)(ipw + (size_t)(j0+1)*D + ci*16);
      float a0 = 0.f, a1 = 0.f;
      #pragma unroll
      for (int c = 0; c < 4; c++){
        float4 qq = qv[c];
        float4 x0 = w0[c];
        float4 x1 = w1r[c];
        a0 += x0.x*qq.x + x0.y*qq.y + x0.z*qq.z + x0.w*qq.w;
        a1 += x1.x*qq.x + x1.y*qq.y + x1.z*qq.z + x1.w*qq.w;
      }
      a0 = wave_sum(a0);
      a1 = wave_sum(a1);
      if (ci == 0){
        qh[w*16 + jj]     = a0 + ipb[j0];
        qh[w*16 + jj + 1] = a1 + ipb[j0 + 1];
      }
    }
  }
  __syncthreads();

  if (t < DH){
    float p = qh[t] * ipb[D + h*DH + t];
    p = wave_sum(p);
    if (t == 0 && sl == 0) sb[h] = p;
  }
  float4 acc = make_float4(0.f,0.f,0.f,0.f);
  for (int jj = 0; jj < 16; jj++){
    int j = w*16 + jj;
    float4 ww = *((const float4*)(ipw + (size_t)(D + h*DH + j)*D) + sl*64 + ci);
    float qj = qh[j];
    acc.x += qj*ww.x; acc.y += qj*ww.y; acc.z += qj*ww.z; acc.w += qj*ww.w;
  }
  red[t] = acc;
  __syncthreads();
  if (w == 0){
    float4 a = red[ci], b1 = red[64+ci], c1 = red[128+ci], d1 = red[192+ci];
    float4 r = make_float4(a.x+b1.x+c1.x+d1.x, a.y+b1.y+c1.y+d1.y,
                           a.z+b1.z+c1.z+d1.z, a.w+b1.w+c1.w+d1.w);
    ((float4*)(qk + h*D))[sl*64 + ci] = r;
  }
}

// scatter-reduce butterfly: 4 per-head partials -> head g=(ci>>4) total in all lanes of group g
__device__ __forceinline__ float bf4(float s0, float s1, float s2, float s3, int ci){
  const bool lo32 = (ci & 32) == 0;
  float za = lo32 ? s2 : s0;
  float ka = lo32 ? s0 : s2;
  float u02 = ka + __shfl_xor(za, 32, 64);
  float zb = lo32 ? s3 : s1;
  float kb = lo32 ? s1 : s3;
  float u13 = kb + __shfl_xor(zb, 32, 64);
  const bool lo16 = (ci & 16) == 0;
  float zc = lo16 ? u13 : u02;
  float kc = lo16 ? u02 : u13;
  float v = kc + __shfl_xor(zc, 16, 64);
  v += __shfl_xor(v, 8, 64);
  v += __shfl_xor(v, 4, 64);
  v += __shfl_xor(v, 2, 64);
  v += __shfl_xor(v, 1, 64);
  return v;
}

// K2: fused scoreless attention. 4 waves, wave w owns heads {4w..4w+3}.
// Row-PAIR software pipeline: two independent butterfly chains interleave to
// hide cross-lane latency. 8-row tiles, double-buffered, 2 blocks/CU.
__global__ __launch_bounds__(256, 2) void g_attn(const float* __restrict__ nbr, const float* __restrict__ qk,
                       const float* __restrict__ sb, float* __restrict__ lpart,
                       float* __restrict__ part, int rows_per_blk){
  __shared__ __align__(16) float tile[2][8*D];   // 64 KiB -> 2 blocks/CU
  const int t = threadIdx.x;
  const int w = t >> 6, ci = t & 63;
  const int wb = t & ~63;
  const int g = (ci >> 4) & 3;
  const float sbl = sb[w*4 + g];

  float qk0[16], qk1[16], qk2[16], qk3[16];
  {
    const float4* p0 = (const float4*)(qk + (w*4+0)*D);
    const float4* p1 = (const float4*)(qk + (w*4+1)*D);
    const float4* p2 = (const float4*)(qk + (w*4+2)*D);
    const float4* p3 = (const float4*)(qk + (w*4+3)*D);
    #pragma unroll
    for (int c = 0; c < 4; c++){
      float4 f;
      f = p0[c*64 + ci]; qk0[4*c]=f.x; qk0[4*c+1]=f.y; qk0[4*c+2]=f.z; qk0[4*c+3]=f.w;
      f = p1[c*64 + ci]; qk1[4*c]=f.x; qk1[4*c+1]=f.y; qk1[4*c+2]=f.z; qk1[4*c+3]=f.w;
      f = p2[c*64 + ci]; qk2[4*c]=f.x; qk2[4*c+1]=f.y; qk2[4*c+2]=f.z; qk2[4*c+3]=f.w;
      f = p3[c*64 + ci]; qk3[4*c]=f.x; qk3[4*c+1]=f.y; qk3[4*c+2]=f.z; qk3[4*c+3]=f.w;
    }
  }
  float acc0[16], acc1[16], acc2[16], acc3[16];
  #pragma unroll
  for (int i = 0; i < 16; i++){ acc0[i]=0.f; acc1[i]=0.f; acc2[i]=0.f; acc3[i]=0.f; }
  float lsum = 0.f;

  const int k0 = blockIdx.x * rows_per_blk;
  const int ntiles = rows_per_blk >> 3;
  const uint4* gb = (const uint4*)nbr;

  {
    const uint4* gsrc = gb + (size_t)k0*256;
    #pragma unroll
    for (int i = 0; i < 8; i++) GLL(gsrc + i*256 + t, &tile[0][(i*256 + wb)*4]);
  }
  __syncthreads();

  #pragma unroll 1
  for (int tl = 0; tl < ntiles; tl++){
    int cur = tl & 1;
    if (tl + 1 < ntiles){
      const uint4* gsrc = gb + (size_t)(k0 + (tl+1)*8)*256;
      #pragma unroll
      for (int i = 0; i < 8; i++) GLL(gsrc + i*256 + t, &tile[cur^1][(i*256 + wb)*4]);
    }
    __builtin_amdgcn_s_setprio(1);
    #pragma unroll 1
    for (int r = 0; r < 8; r += 2){
      const float4* rowA = (const float4*)(tile[cur]) + r*256;
      float xfA[16], xfB[16];
      float sA0=0.f,sA1=0.f,sA2=0.f,sA3=0.f;
      float sB0=0.f,sB1=0.f,sB2=0.f,sB3=0.f;
      #pragma unroll
      for (int c = 0; c < 4; c++){
        float4 a = rowA[c*64 + ci];
        xfA[4*c]=a.x; xfA[4*c+1]=a.y; xfA[4*c+2]=a.z; xfA[4*c+3]=a.w;
        sA0 += a.x*qk0[4*c] + a.y*qk0[4*c+1] + a.z*qk0[4*c+2] + a.w*qk0[4*c+3];
        sA1 += a.x*qk1[4*c] + a.y*qk1[4*c+1] + a.z*qk1[4*c+2] + a.w*qk1[4*c+3];
        sA2 += a.x*qk2[4*c] + a.y*qk2[4*c+1] + a.z*qk2[4*c+2] + a.w*qk2[4*c+3];
        sA3 += a.x*qk3[4*c] + a.y*qk3[4*c+1] + a.z*qk3[4*c+2] + a.w*qk3[4*c+3];
      }
      #pragma unroll
      for (int c = 0; c < 4; c++){
        float4 a = rowA[256 + c*64 + ci];
        xfB[4*c]=a.x; xfB[4*c+1]=a.y; xfB[4*c+2]=a.z; xfB[4*c+3]=a.w;
        sB0 += a.x*qk0[4*c] + a.y*qk0[4*c+1] + a.z*qk0[4*c+2] + a.w*qk0[4*c+3];
        sB1 += a.x*qk1[4*c] + a.y*qk1[4*c+1] + a.z*qk1[4*c+2] + a.w*qk1[4*c+3];
        sB2 += a.x*qk2[4*c] + a.y*qk2[4*c+1] + a.z*qk2[4*c+2] + a.w*qk2[4*c+3];
        sB3 += a.x*qk3[4*c] + a.y*qk3[4*c+1] + a.z*qk3[4*c+2] + a.w*qk3[4*c+3];
      }
      float vA = bf4(sA0, sA1, sA2, sA3, ci);
      float vB = bf4(sB0, sB1, sB2, sB3, ci);
      float pA = __expf((vA + sbl)*0.125f);
      float pB = __expf((vB + sbl)*0.125f);
      lsum += pA + pB;
      float pA0 = __shfl(pA, 0, 64), pA1 = __shfl(pA, 16, 64);
      float pA2 = __shfl(pA, 32, 64), pA3 = __shfl(pA, 48, 64);
      float pB0 = __shfl(pB, 0, 64), pB1 = __shfl(pB, 16, 64);
      float pB2 = __shfl(pB, 32, 64), pB3 = __shfl(pB, 48, 64);
      #pragma unroll
      for (int j = 0; j < 16; j++){
        acc0[j] += pA0*xfA[j] + pB0*xfB[j];
        acc1[j] += pA1*xfA[j] + pB1*xfB[j];
        acc2[j] += pA2*xfA[j] + pB2*xfB[j];
        acc3[j] += pA3*xfA[j] + pB3*xfB[j];
      }
    }
    __builtin_amdgcn_s_setprio(0);
    __syncthreads();
  }

  if ((ci & 15) == 0) lpart[blockIdx.x*H + w*4 + g] = lsum;
  float4* o = (float4*)(part + (size_t)blockIdx.x*(H*D) + (size_t)(w*4)*D);
  #pragma unroll
  for (int c = 0; c < 4; c++){
    o[0*256 + c*64 + ci] = make_float4(acc0[4*c], acc0[4*c+1], acc0[4*c+2], acc0[4*c+3]);
    o[1*256 + c*64 + ci] = make_float4(acc1[4*c], acc1[4*c+1], acc1[4*c+2], acc1[4*c+3]);
    o[2*256 + c*64 + ci] = make_float4(acc2[4*c], acc2[4*c+1], acc2[4*c+2], acc2[4*c+3]);
    o[3*256 + c*64 + ci] = make_float4(acc3[4*c], acc3[4*c+1], acc3[4*c+2], acc3[4*c+3]);
  }
}

// K3: nb[o] = sum_b part[b][o] with 16-way K-split, 1024-thread blocks
// (serial chain 32 loads/thread vs 128 before); block 256 reduces lpart -> lh.
__global__ __launch_bounds__(1024) void g_red(const float* __restrict__ part, const float* __restrict__ lpart,
                                              float* __restrict__ nb, float* __restrict__ lh, int nblk){
  int b = blockIdx.x, t = threadIdx.x;
  __shared__ float red[1024];
  if (b == 256){
    if (t < 256){
      int hh = t & 15, cs = t >> 4, per = nblk >> 4;
      float s = 0.f;
      for (int k = 0; k < per; k++) s += lpart[(cs*per + k)*H + hh];
      red[t] = s;
    }
    __syncthreads();
    if (t < 16){
      float a = 0.f;
      #pragma unroll
      for (int i = 0; i < 16; i++) a += red[i*16 + t];
      lh[t] = a;
    }
    return;
  }
  int o0 = b * 64;
  int oo = t & 63, cs = t >> 6;           // 16 slices over nblk
  int per = nblk >> 4;
  float s = 0.f;
  #pragma unroll 8
  for (int k = 0; k < per; k++) s += part[(size_t)(cs*per + k)*(H*D) + o0 + oo];
  red[t] = s;
  __syncthreads();
  if (t < 64){
    float a = 0.f;
    #pragma unroll
    for (int i = 0; i < 16; i++) a += red[i*64 + t];
    nb[o0 + t] = a;
  }
}

// K4: ctx[j] = wv_row(j) . (nb[h]/lh[h]) + bv[j]
__global__ void g_ctx(const float* __restrict__ ipw, const float* __restrict__ ipb,
                      const float* __restrict__ nb, const float* __restrict__ lh,
                      float* __restrict__ ctx){
  int j = blockIdx.x, l = threadIdx.x, h = j >> 6;
  const float4* wv = (const float4*)(ipw + (size_t)(2*D + j)*D + l*16);
  const float4* nv = (const float4*)(nb + h*D + l*16);
  float acc = 0.f;
  #pragma unroll
  for (int t = 0; t < 4; t++){
    float4 b = wv[t], n = nv[t];
    acc += b.x*n.x + b.y*n.y + b.z*n.z + b.w*n.w;
  }
  acc = wave_sum(acc);
  if (l == 0) ctx[j] = acc/lh[h] + ipb[2*D + j];
}

// K5: xb[j] = query[j] + out_proj_w_row(j) . ctx + out_proj_b[j]
__global__ void g_attnout(const float* __restrict__ opw, const float* __restrict__ opb,
                          const float* __restrict__ query, const float* __restrict__ ctx,
                          float* __restrict__ xb){
  int j = blockIdx.x, l = threadIdx.x;
  const float4* wv = (const float4*)(opw + (size_t)j*D + l*16);
  const float4* cv = (const float4*)(ctx + l*16);
  float acc = 0.f;
  #pragma unroll
  for (int t = 0; t < 4; t++){
    float4 b = wv[t], c = cv[t];
    acc += b.x*c.x + b.y*c.y + b.z*c.z + b.w*c.w;
  }
  acc = wave_sum(acc);
  if (l == 0) xb[j] = query[j] + acc + opb[j];
}

// K6: fused LN1 + FFN1. 256 blocks x 256 thr; block computes LN(xb) locally into LDS,
// block 0 also persists it to xln (needed for final residual); then 16 gelu-matvec rows.
__global__ __launch_bounds__(256) void g_ffn1(const float* __restrict__ w1, const float* __restrict__ b1,
                                              const float* __restrict__ xb,
                                              const float* __restrict__ g1, const float* __restrict__ be1,
                                              float* __restrict__ xln, float* __restrict__ h1){
  int t = threadIdx.x, b = blockIdx.x;
  __shared__ float xs[D];
  __shared__ float red[8];
  float4 v = ((const float4*)xb)[t];
  float s = wave_sum(v.x + v.y + v.z + v.w);
  if ((t & 63) == 0) red[t >> 6] = s;
  __syncthreads();
  float m = (red[0]+red[1]+red[2]+red[3]) * (1.0f/D);
  float4 d = make_float4(v.x-m, v.y-m, v.z-m, v.w-m);
  float s2 = wave_sum(d.x*d.x + d.y*d.y + d.z*d.z + d.w*d.w);
  if ((t & 63) == 0) red[4 + (t >> 6)] = s2;
  __syncthreads();
  float var = (red[4]+red[5]+red[6]+red[7]) * (1.0f/D);
  float rs = rsqrtf(var + EPS);
  float4 gg = ((const float4*)g1)[t], bb = ((const float4*)be1)[t];
  float4 r = make_float4(d.x*rs*gg.x + bb.x, d.y*rs*gg.y + bb.y,
                         d.z*rs*gg.z + bb.z, d.w*rs*gg.w + bb.w);
  ((float4*)xs)[t] = r;
  if (b == 0) ((float4*)xln)[t] = r;
  __syncthreads();

  int w = t >> 6, l = t & 63;
  const float4* xs4 = (const float4*)xs;
  #pragma unroll 1
  for (int rr = 0; rr < 4; rr++){
    int j = b*16 + w*4 + rr;
    const float4* wr = (const float4*)(w1 + (size_t)j*D);
    float a = 0.f;
    #pragma unroll
    for (int c = 0; c < 4; c++){
      float4 ww = wr[c*64 + l], xx = xs4[c*64 + l];
      a += ww.x*xx.x + ww.y*xx.y + ww.z*xx.z + ww.w*xx.w;
    }
    a = wave_sum(a);
    if (l == 0){
      float z = a + b1[j];
      h1[j] = 0.5f*z*(1.0f + erff(z*0.70710678118654752f));
    }
  }
}

// K7: y[j] = w2_row(j) . h1 + b2[j]   (row length 4096)
__global__ void g_ffn2(const float* __restrict__ w2, const float* __restrict__ b2v,
                       const float* __restrict__ h1, float* __restrict__ y){
  int j = blockIdx.x, l = threadIdx.x;
  const float4* wv = (const float4*)(w2 + (size_t)j*4096 + l*64);
  const float4* hv = (const float4*)(h1 + l*64);
  float acc = 0.f;
  #pragma unroll
  for (int t = 0; t < 16; t++){
    float4 b = wv[t], hh = hv[t];
    acc += b.x*hh.x + b.y*hh.y + b.z*hh.z + b.w*hh.w;
  }
  acc = wave_sum(acc);
  if (l == 0) y[j] = acc + b2v[j];
}

// K8: out = LN(xln + y)*g2 + be2
__global__ __launch_bounds__(1024) void g_ln2(const float* __restrict__ xln, const float* __restrict__ y,
                                              const float* __restrict__ g, const float* __restrict__ be,
                                              float* __restrict__ out){
  int t = threadIdx.x;
  __shared__ float red[16];
  __shared__ float bc;
  float v = xln[t] + y[t];
  float s = wave_sum(v);
  if ((t & 63) == 0) red[t >> 6] = s;
  __syncthreads();
  if (t == 0){ float a = 0.f; for (int i = 0; i < 16; i++) a += red[i]; bc = a*(1.0f/D); }
  __syncthreads();
  float m = bc;
  float d = v - m;
  float s2 = wave_sum(d*d);
  if ((t & 63) == 0) red[t >> 6] = s2;
  __syncthreads();
  if (t == 0){ float a = 0.f; for (int i = 0; i < 16; i++) a += red[i]; bc = a*(1.0f/D); }
  __syncthreads();
  float rs = rsqrtf(bc + EPS);
  out[t] = d*rs*g[t] + be[t];
}

extern "C" void kernel_launch(void* const* d_in, const int* in_sizes, int n_in,
                              void* d_out, int out_size, void* d_ws, size_t ws_size,
                              hipStream_t stream) {
  const float* query = (const float*)d_in[0];
  const float* nbr   = (const float*)d_in[1];
  const float* ipw   = (const float*)d_in[2];
  const float* ipb   = (const float*)d_in[3];
  const float* opw   = (const float*)d_in[4];
  const float* opb   = (const float*)d_in[5];
  const float* w1    = (const float*)d_in[6];
  const float* b1    = (const float*)d_in[7];
  const float* w2    = (const float*)d_in[8];
  const float* b2v   = (const float*)d_in[9];
  const float* g1    = (const float*)d_in[10];
  const float* be1   = (const float*)d_in[11];
  const float* g2    = (const float*)d_in[12];
  const float* be2   = (const float*)d_in[13];

  float* ws    = (float*)d_ws;
  float* qk    = ws;               // 16384
  float* sb    = qk + H*D;         // 16
  float* lh    = sb + 16;          // 16
  float* ctx   = lh + 16;          // 1024
  float* xb    = ctx + D;          // 1024
  float* xln   = xb + D;           // 1024
  float* h1    = xln + D;          // 4096
  float* y     = h1 + 4*D;         // 1024
  float* nb    = y + D;            // 16384
  float* lpart = nb + H*D;         // 512*16 = 8192 (max)
  float* part  = lpart + 8192;     // nblk*16384

  size_t fixed_bytes = (size_t)(part - ws) * 4;
  int nblk = 512;
  while (nblk > 64 && fixed_bytes + (size_t)nblk*H*D*4 > ws_size) nblk >>= 1;
  int rows_per_blk = KN / nblk;

  g_qk     <<<64, 256, 0, stream>>>(query, ipw, ipb, qk, sb);
  g_attn   <<<nblk, 256, 0, stream>>>(nbr, qk, sb, lpart, part, rows_per_blk);
  g_red    <<<257, 1024, 0, stream>>>(part, lpart, nb, lh, nblk);
  g_ctx    <<<1024, 64, 0, stream>>>(ipw, ipb, nb, lh, ctx);
  g_attnout<<<1024, 64, 0, stream>>>(opw, opb, query, ctx, xb);
  g_ffn1   <<<256, 256, 0, stream>>>(w1, b1, xb, g1, be1, xln, h1);
  g_ffn2   <<<1024, 64, 0, stream>>>(w2, b2v, h1, y);
  g_ln2    <<<1, 1024, 0, stream>>>(xln, y, g2, be2, (float*)d_out);
}

// Round 5
// 302.818 us; speedup vs baseline: 1.4299x; 1.0133x over previous
//
#include <hip/hip_runtime.h>
#include <hip/hip_bf16.h>

#define D 1024
#define H 16
#define DH 64
#define KN 32768
#define EPS 1e-5f

__device__ __forceinline__ float wave_sum(float v){
  #pragma unroll
  for (int off = 32; off; off >>= 1) v += __shfl_xor(v, off, 64);
  return v;
}

#define GLL(gp, lp) __builtin_amdgcn_global_load_lds((const __attribute__((address_space(1))) void*)(gp), (__attribute__((address_space(3))) void*)(lp), 16, 0, 0)

// K1: merged qproj+qk. 64 blocks (head h = b>>2, col slice sl = b&3).
__global__ __launch_bounds__(256) void g_qk(const float* __restrict__ query,
                                            const float* __restrict__ ipw, const float* __restrict__ ipb,
                                            float* __restrict__ qk, float* __restrict__ sb){
  int b = blockIdx.x, t = threadIdx.x;
  int h = b >> 2, sl = b & 3;
  int w = t >> 6, ci = t & 63;
  __shared__ float qh[DH];
  __shared__ float4 red[256];

  // phase 1: 16 rows per wave, 2-row ILP (per-row math identical to round-1 g_qproj)
  {
    const float4* qv = (const float4*)(query + ci*16);
    #pragma unroll 1
    for (int jj = 0; jj < 16; jj += 2){
      int j0 = h*DH + w*16 + jj;
      const float4* w0 = (const float4*)(ipw + (size_t)j0*D + ci*16);
      const float4* w1r = (const float4*)(ipw + (size_t)(j0+1)*D + ci*16);
      float a0 = 0.f, a1 = 0.f;
      #pragma unroll
      for (int c = 0; c < 4; c++){
        float4 qq = qv[c];
        float4 x0 = w0[c];
        float4 x1 = w1r[c];
        a0 += x0.x*qq.x + x0.y*qq.y + x0.z*qq.z + x0.w*qq.w;
        a1 += x1.x*qq.x + x1.y*qq.y + x1.z*qq.z + x1.w*qq.w;
      }
      a0 = wave_sum(a0);
      a1 = wave_sum(a1);
      if (ci == 0){
        qh[w*16 + jj]     = a0 + ipb[j0];
        qh[w*16 + jj + 1] = a1 + ipb[j0 + 1];
      }
    }
  }
  __syncthreads();

  if (t < DH){
    float p = qh[t] * ipb[D + h*DH + t];
    p = wave_sum(p);
    if (t == 0 && sl == 0) sb[h] = p;
  }
  float4 acc = make_float4(0.f,0.f,0.f,0.f);
  for (int jj = 0; jj < 16; jj++){
    int j = w*16 + jj;
    float4 ww = *((const float4*)(ipw + (size_t)(D + h*DH + j)*D) + sl*64 + ci);
    float qj = qh[j];
    acc.x += qj*ww.x; acc.y += qj*ww.y; acc.z += qj*ww.z; acc.w += qj*ww.w;
  }
  red[t] = acc;
  __syncthreads();
  if (w == 0){
    float4 a = red[ci], b1 = red[64+ci], c1 = red[128+ci], d1 = red[192+ci];
    float4 r = make_float4(a.x+b1.x+c1.x+d1.x, a.y+b1.y+c1.y+d1.y,
                           a.z+b1.z+c1.z+d1.z, a.w+b1.w+c1.w+d1.w);
    ((float4*)(qk + h*D))[sl*64 + ci] = r;
  }
}

// K2: fused scoreless attention v4. 512 threads = 8 waves; wave w owns heads {2w, 2w+1}
// (qk frags 32 VGPR, acc 32 VGPR -> ~105 VGPR total => 4 waves/SIMD with launch_bounds(512,4)).
// Per row: 2 per-head dot partials -> 2-group scatter butterfly (6 shfl), one exp/lane,
// 2 broadcasts, 32-FMA accumulate. 8-row tiles double-buffered (64 KiB), 2 blocks/CU.
__global__ __launch_bounds__(512, 4) void g_attn(const float* __restrict__ nbr, const float* __restrict__ qk,
                       const float* __restrict__ sb, float* __restrict__ lpart,
                       float* __restrict__ part, int rows_per_blk){
  __shared__ __align__(16) float tile[2][8*D];   // 64 KiB -> 2 blocks/CU (128 KiB)
  const int t = threadIdx.x;
  const int w = t >> 6, ci = t & 63;
  const int wb = t & ~63;                 // wave-uniform lane base
  const int g = (ci >> 5) & 1;            // head group within wave
  const float sbl = sb[w*2 + g];

  float qk0[16], qk1[16];
  {
    const float4* p0 = (const float4*)(qk + (w*2+0)*D);
    const float4* p1 = (const float4*)(qk + (w*2+1)*D);
    #pragma unroll
    for (int c = 0; c < 4; c++){
      float4 f;
      f = p0[c*64 + ci]; qk0[4*c]=f.x; qk0[4*c+1]=f.y; qk0[4*c+2]=f.z; qk0[4*c+3]=f.w;
      f = p1[c*64 + ci]; qk1[4*c]=f.x; qk1[4*c+1]=f.y; qk1[4*c+2]=f.z; qk1[4*c+3]=f.w;
    }
  }
  float acc0[16], acc1[16];
  #pragma unroll
  for (int i = 0; i < 16; i++){ acc0[i]=0.f; acc1[i]=0.f; }
  float lsum = 0.f;

  const int k0 = blockIdx.x * rows_per_blk;
  const int ntiles = rows_per_blk >> 3;
  const uint4* gb = (const uint4*)nbr;

  // prefetch tile 0: 8 rows = 2048 float4s, 4 per thread
  {
    const uint4* gsrc = gb + (size_t)k0*256;
    #pragma unroll
    for (int i = 0; i < 4; i++) GLL(gsrc + i*512 + t, &tile[0][(i*512 + wb)*4]);
  }
  __syncthreads();

  #pragma unroll 1
  for (int tl = 0; tl < ntiles; tl++){
    int cur = tl & 1;
    if (tl + 1 < ntiles){
      const uint4* gsrc = gb + (size_t)(k0 + (tl+1)*8)*256;
      #pragma unroll
      for (int i = 0; i < 4; i++) GLL(gsrc + i*512 + t, &tile[cur^1][(i*512 + wb)*4]);
    }
    #pragma unroll 1
    for (int r = 0; r < 8; r++){
      const float4* row4 = (const float4*)(tile[cur]) + r*256;
      float xf[16];
      float s0 = 0.f, s1 = 0.f;
      #pragma unroll
      for (int c = 0; c < 4; c++){
        float4 a = row4[c*64 + ci];          // stride-1 across lanes: conflict-free
        xf[4*c]=a.x; xf[4*c+1]=a.y; xf[4*c+2]=a.z; xf[4*c+3]=a.w;
        s0 += a.x*qk0[4*c] + a.y*qk0[4*c+1] + a.z*qk0[4*c+2] + a.w*qk0[4*c+3];
        s1 += a.x*qk1[4*c] + a.y*qk1[4*c+1] + a.z*qk1[4*c+2] + a.w*qk1[4*c+3];
      }
      // 2-group scatter butterfly: lo half -> head 2w total, hi half -> head 2w+1
      bool lo = (ci & 32) == 0;
      float z = lo ? s1 : s0;
      float k = lo ? s0 : s1;
      float v = k + __shfl_xor(z, 32, 64);
      v += __shfl_xor(v, 16, 64);
      v += __shfl_xor(v, 8, 64);
      v += __shfl_xor(v, 4, 64);
      v += __shfl_xor(v, 2, 64);
      v += __shfl_xor(v, 1, 64);
      float pv = __expf((v + sbl)*0.125f);
      lsum += pv;                            // group g lanes hold head (2w+g)'s p
      float pa = __shfl(pv, 0, 64);
      float pb = __shfl(pv, 32, 64);
      #pragma unroll
      for (int j = 0; j < 16; j++){
        acc0[j] += pa*xf[j];
        acc1[j] += pb*xf[j];
      }
    }
    __syncthreads();
  }

  if ((ci & 31) == 0) lpart[blockIdx.x*H + w*2 + g] = lsum;
  float4* o = (float4*)(part + (size_t)blockIdx.x*(H*D) + (size_t)(w*2)*D);
  #pragma unroll
  for (int c = 0; c < 4; c++){
    o[c*64 + ci]       = make_float4(acc0[4*c], acc0[4*c+1], acc0[4*c+2], acc0[4*c+3]);
    o[256 + c*64 + ci] = make_float4(acc1[4*c], acc1[4*c+1], acc1[4*c+2], acc1[4*c+3]);
  }
}

// K3: nb[o] = sum_b part[b][o] with 16-way K-split, 1024-thread blocks;
// block 256 reduces lpart -> lh.
__global__ __launch_bounds__(1024) void g_red(const float* __restrict__ part, const float* __restrict__ lpart,
                                              float* __restrict__ nb, float* __restrict__ lh, int nblk){
  int b = blockIdx.x, t = threadIdx.x;
  __shared__ float red[1024];
  if (b == 256){
    if (t < 256){
      int hh = t & 15, cs = t >> 4, per = nblk >> 4;
      float s = 0.f;
      for (int k = 0; k < per; k++) s += lpart[(cs*per + k)*H + hh];
      red[t] = s;
    }
    __syncthreads();
    if (t < 16){
      float a = 0.f;
      #pragma unroll
      for (int i = 0; i < 16; i++) a += red[i*16 + t];
      lh[t] = a;
    }
    return;
  }
  int o0 = b * 64;
  int oo = t & 63, cs = t >> 6;           // 16 slices over nblk
  int per = nblk >> 4;
  float s = 0.f;
  #pragma unroll 8
  for (int k = 0; k < per; k++) s += part[(size_t)(cs*per + k)*(H*D) + o0 + oo];
  red[t] = s;
  __syncthreads();
  if (t < 64){
    float a = 0.f;
    #pragma unroll
    for (int i = 0; i < 16; i++) a += red[i*64 + t];
    nb[o0 + t] = a;
  }
}

// K4: ctx[j] = wv_row(j) . (nb[h]/lh[h]) + bv[j]
__global__ void g_ctx(const float* __restrict__ ipw, const float* __restrict__ ipb,
                      const float* __restrict__ nb, const float* __restrict__ lh,
                      float* __restrict__ ctx){
  int j = blockIdx.x, l = threadIdx.x, h = j >> 6;
  const float4* wv = (const float4*)(ipw + (size_t)(2*D + j)*D + l*16);
  const float4* nv = (const float4*)(nb + h*D + l*16);
  float acc = 0.f;
  #pragma unroll
  for (int t = 0; t < 4; t++){
    float4 b = wv[t], n = nv[t];
    acc += b.x*n.x + b.y*n.y + b.z*n.z + b.w*n.w;
  }
  acc = wave_sum(acc);
  if (l == 0) ctx[j] = acc/lh[h] + ipb[2*D + j];
}

// K5: xb[j] = query[j] + out_proj_w_row(j) . ctx + out_proj_b[j]
__global__ void g_attnout(const float* __restrict__ opw, const float* __restrict__ opb,
                          const float* __restrict__ query, const float* __restrict__ ctx,
                          float* __restrict__ xb){
  int j = blockIdx.x, l = threadIdx.x;
  const float4* wv = (const float4*)(opw + (size_t)j*D + l*16);
  const float4* cv = (const float4*)(ctx + l*16);
  float acc = 0.f;
  #pragma unroll
  for (int t = 0; t < 4; t++){
    float4 b = wv[t], c = cv[t];
    acc += b.x*c.x + b.y*c.y + b.z*c.z + b.w*c.w;
  }
  acc = wave_sum(acc);
  if (l == 0) xb[j] = query[j] + acc + opb[j];
}

// K6: fused LN1 + FFN1. 256 blocks x 256 thr; block computes LN(xb) locally into LDS,
// block 0 also persists it to xln (needed for final residual); then 16 gelu-matvec rows.
__global__ __launch_bounds__(256) void g_ffn1(const float* __restrict__ w1, const float* __restrict__ b1,
                                              const float* __restrict__ xb,
                                              const float* __restrict__ g1, const float* __restrict__ be1,
                                              float* __restrict__ xln, float* __restrict__ h1){
  int t = threadIdx.x, b = blockIdx.x;
  __shared__ float xs[D];
  __shared__ float red[8];
  float4 v = ((const float4*)xb)[t];
  float s = wave_sum(v.x + v.y + v.z + v.w);
  if ((t & 63) == 0) red[t >> 6] = s;
  __syncthreads();
  float m = (red[0]+red[1]+red[2]+red[3]) * (1.0f/D);
  float4 d = make_float4(v.x-m, v.y-m, v.z-m, v.w-m);
  float s2 = wave_sum(d.x*d.x + d.y*d.y + d.z*d.z + d.w*d.w);
  if ((t & 63) == 0) red[4 + (t >> 6)] = s2;
  __syncthreads();
  float var = (red[4]+red[5]+red[6]+red[7]) * (1.0f/D);
  float rs = rsqrtf(var + EPS);
  float4 gg = ((const float4*)g1)[t], bb = ((const float4*)be1)[t];
  float4 r = make_float4(d.x*rs*gg.x + bb.x, d.y*rs*gg.y + bb.y,
                         d.z*rs*gg.z + bb.z, d.w*rs*gg.w + bb.w);
  ((float4*)xs)[t] = r;
  if (b == 0) ((float4*)xln)[t] = r;
  __syncthreads();

  int w = t >> 6, l = t & 63;
  const float4* xs4 = (const float4*)xs;
  #pragma unroll 1
  for (int rr = 0; rr < 4; rr++){
    int j = b*16 + w*4 + rr;
    const float4* wr = (const float4*)(w1 + (size_t)j*D);
    float a = 0.f;
    #pragma unroll
    for (int c = 0; c < 4; c++){
      float4 ww = wr[c*64 + l], xx = xs4[c*64 + l];
      a += ww.x*xx.x + ww.y*xx.y + ww.z*xx.z + ww.w*xx.w;
    }
    a = wave_sum(a);
    if (l == 0){
      float z = a + b1[j];
      h1[j] = 0.5f*z*(1.0f + erff(z*0.70710678118654752f));
    }
  }
}

// K7: y[j] = w2_row(j) . h1 + b2[j]   (row length 4096; lane-stride-1 coalesced reads)
__global__ void g_ffn2(const float* __restrict__ w2, const float* __restrict__ b2v,
                       const float* __restrict__ h1, float* __restrict__ y){
  int j = blockIdx.x, l = threadIdx.x;
  const float4* wr = (const float4*)(w2 + (size_t)j*4096);
  const float4* hv = (const float4*)h1;
  float acc = 0.f;
  #pragma unroll
  for (int c = 0; c < 16; c++){
    float4 ww = wr[c*64 + l], hh = hv[c*64 + l];
    acc += ww.x*hh.x + ww.y*hh.y + ww.z*hh.z + ww.w*hh.w;
  }
  acc = wave_sum(acc);
  if (l == 0) y[j] = acc + b2v[j];
}

// K8: out = LN(xln + y)*g2 + be2
__global__ __launch_bounds__(1024) void g_ln2(const float* __restrict__ xln, const float* __restrict__ y,
                                              const float* __restrict__ g, const float* __restrict__ be,
                                              float* __restrict__ out){
  int t = threadIdx.x;
  __shared__ float red[16];
  __shared__ float bc;
  float v = xln[t] + y[t];
  float s = wave_sum(v);
  if ((t & 63) == 0) red[t >> 6] = s;
  __syncthreads();
  if (t == 0){ float a = 0.f; for (int i = 0; i < 16; i++) a += red[i]; bc = a*(1.0f/D); }
  __syncthreads();
  float m = bc;
  float d = v - m;
  float s2 = wave_sum(d*d);
  if ((t & 63) == 0) red[t >> 6] = s2;
  __syncthreads();
  if (t == 0){ float a = 0.f; for (int i = 0; i < 16; i++) a += red[i]; bc = a*(1.0f/D); }
  __syncthreads();
  float rs = rsqrtf(bc + EPS);
  out[t] = d*rs*g[t] + be[t];
}

extern "C" void kernel_launch(void* const* d_in, const int* in_sizes, int n_in,
                              void* d_out, int out_size, void* d_ws, size_t ws_size,
                              hipStream_t stream) {
  const float* query = (const float*)d_in[0];
  const float* nbr   = (const float*)d_in[1];
  const float* ipw   = (const float*)d_in[2];
  const float* ipb   = (const float*)d_in[3];
  const float* opw   = (const float*)d_in[4];
  const float* opb   = (const float*)d_in[5];
  const float* w1    = (const float*)d_in[6];
  const float* b1    = (const float*)d_in[7];
  const float* w2    = (const float*)d_in[8];
  const float* b2v   = (const float*)d_in[9];
  const float* g1    = (const float*)d_in[10];
  const float* be1   = (const float*)d_in[11];
  const float* g2    = (const float*)d_in[12];
  const float* be2   = (const float*)d_in[13];

  float* ws    = (float*)d_ws;
  float* qk    = ws;               // 16384
  float* sb    = qk + H*D;         // 16
  float* lh    = sb + 16;          // 16
  float* ctx   = lh + 16;          // 1024
  float* xb    = ctx + D;          // 1024
  float* xln   = xb + D;           // 1024
  float* h1    = xln + D;          // 4096
  float* y     = h1 + 4*D;         // 1024
  float* nb    = y + D;            // 16384
  float* lpart = nb + H*D;         // 512*16 = 8192 (max)
  float* part  = lpart + 8192;     // nblk*16384

  size_t fixed_bytes = (size_t)(part - ws) * 4;
  int nblk = 512;
  while (nblk > 64 && fixed_bytes + (size_t)nblk*H*D*4 > ws_size) nblk >>= 1;
  int rows_per_blk = KN / nblk;

  g_qk     <<<64, 256, 0, stream>>>(query, ipw, ipb, qk, sb);
  g_attn   <<<nblk, 512, 0, stream>>>(nbr, qk, sb, lpart, part, rows_per_blk);
  g_red    <<<257, 1024, 0, stream>>>(part, lpart, nb, lh, nblk);
  g_ctx    <<<1024, 64, 0, stream>>>(ipw, ipb, nb, lh, ctx);
  g_attnout<<<1024, 64, 0, stream>>>(opw, opb, query, ctx, xb);
  g_ffn1   <<<256, 256, 0, stream>>>(w1, b1, xb, g1, be1, xln, h1);
  g_ffn2   <<<1024, 64, 0, stream>>>(w2, b2v, h1, y);
  g_ln2    <<<1, 1024, 0, stream>>>(xln, y, g2, be2, (float*)d_out);
}